// Round 1
// baseline (74.838 us; speedup 1.0000x reference)
//
#include <hip/hip_runtime.h>

#define BB   16
#define NN   4096
#define DD   3
#define QPT  4                 // queries per thread (register tile)
#define TPB  256               // threads per block
#define QPB  (QPT * TPB)       // 1024 queries per block
#define SPLIT 4                // database split across blocks
#define SLICE (NN / SPLIT)     // 1024 db points per block

__global__ __launch_bounds__(256) void chamfer_init_out(float* __restrict__ out) {
    int i = blockIdx.x * 256 + threadIdx.x;
    out[i] = 3.0e38f;
}

__global__ __launch_bounds__(TPB) void chamfer_main(
    const float* __restrict__ xyz1,
    const float* __restrict__ xyz2,
    float* __restrict__ out) {
    // SoA db slice in LDS: s[0]=x, s[1]=y, s[2]=z
    __shared__ __align__(16) float s[3][SLICE];

    const int qtile = blockIdx.x;          // 0..N/QPB-1
    const int b     = blockIdx.y;          // 0..B-1
    const int z     = blockIdx.z;          // 0..2*SPLIT-1
    const int dir   = z & 1;               // 0: dist1 (q=xyz1,db=xyz2), 1: dist2
    const int split = z >> 1;              // 0..SPLIT-1

    const float* qbase = (dir == 0 ? xyz1 : xyz2) + b * NN * DD;
    const float* dbase = (dir == 0 ? xyz2 : xyz1) + b * NN * DD;

    // ---- stage db slice into LDS (SoA) ----
    const float* g = dbase + split * SLICE * DD;
    for (int idx = threadIdx.x; idx < SLICE * DD; idx += TPB) {
        float v = g[idx];
        int p = idx / 3;
        int c = idx - 3 * p;
        s[c][p] = v;
    }
    __syncthreads();

    // ---- load my 4 query points into registers ----
    const int q0 = qtile * QPB + threadIdx.x;
    float qx[QPT], qy[QPT], qz[QPT], bA[QPT], bB[QPT];
#pragma unroll
    for (int i = 0; i < QPT; ++i) {
        const float* p = qbase + (q0 + i * TPB) * DD;
        qx[i] = p[0];
        qy[i] = p[1];
        qz[i] = p[2];
        bA[i] = 3.0e38f;
        bB[i] = 3.0e38f;
    }

    // ---- sweep db slice, 4 points at a time via broadcast b128 reads ----
    for (int j = 0; j < SLICE; j += 4) {
        const float4 X = *(const float4*)&s[0][j];
        const float4 Y = *(const float4*)&s[1][j];
        const float4 Z = *(const float4*)&s[2][j];
#pragma unroll
        for (int i = 0; i < QPT; ++i) {
            float dx0 = qx[i] - X.x, dy0 = qy[i] - Y.x, dz0 = qz[i] - Z.x;
            float dx1 = qx[i] - X.y, dy1 = qy[i] - Y.y, dz1 = qz[i] - Z.y;
            float dx2 = qx[i] - X.z, dy2 = qy[i] - Y.z, dz2 = qz[i] - Z.z;
            float dx3 = qx[i] - X.w, dy3 = qy[i] - Y.w, dz3 = qz[i] - Z.w;
            float d0 = fmaf(dz0, dz0, fmaf(dy0, dy0, dx0 * dx0));
            float d1 = fmaf(dz1, dz1, fmaf(dy1, dy1, dx1 * dx1));
            float d2 = fmaf(dz2, dz2, fmaf(dy2, dy2, dx2 * dx2));
            float d3 = fmaf(dz3, dz3, fmaf(dy3, dy3, dx3 * dx3));
            bA[i] = fminf(bA[i], fminf(d0, d1));
            bB[i] = fminf(bB[i], fminf(d2, d3));
        }
    }

    // ---- combine partials across M-splits via int atomicMin (d2 >= 0) ----
    const int obase = dir * (BB * NN) + b * NN + q0;
#pragma unroll
    for (int i = 0; i < QPT; ++i) {
        float best = fminf(bA[i], bB[i]);
        atomicMin((int*)out + obase + i * TPB, __float_as_int(best));
    }
}

extern "C" void kernel_launch(void* const* d_in, const int* in_sizes, int n_in,
                              void* d_out, int out_size, void* d_ws, size_t ws_size,
                              hipStream_t stream) {
    const float* xyz1 = (const float*)d_in[0];
    const float* xyz2 = (const float*)d_in[1];
    float* out = (float*)d_out;

    // init output to +inf-ish (poisoned to 0xAA by harness; must rewrite every call)
    hipLaunchKernelGGL(chamfer_init_out, dim3(2 * BB * NN / 256), dim3(256), 0, stream, out);

    dim3 grid(NN / QPB, BB, 2 * SPLIT);
    hipLaunchKernelGGL(chamfer_main, grid, dim3(TPB), 0, stream, xyz1, xyz2, out);
}

// Round 2
// 49.363 us; speedup vs baseline: 1.5161x; 1.5161x over previous
//
#include <hip/hip_runtime.h>

#define BB    16
#define NN    4096
#define DD    3
#define QPT   8                  // queries per thread (register tile)
#define TPB   256                // threads per block
#define QPB   (QPT * TPB)        // 2048 queries per block
#define QTILES (NN / QPB)        // 2
#define SPLIT 16                 // database split across blocks
#define SLICE (NN / SPLIT)       // 256 db points per block

__global__ __launch_bounds__(256) void chamfer_init_out(float* __restrict__ out) {
    int i = blockIdx.x * 256 + threadIdx.x;
    out[i] = 3.0e38f;
}

__global__ __launch_bounds__(TPB) void chamfer_main(
    const float* __restrict__ xyz1,
    const float* __restrict__ xyz2,
    float* __restrict__ out) {
    // SoA db slice in LDS: x, y, z, h = x^2+y^2+z^2
    __shared__ __align__(16) float sx[SLICE];
    __shared__ __align__(16) float sy[SLICE];
    __shared__ __align__(16) float sz[SLICE];
    __shared__ __align__(16) float sh[SLICE];

    const int tid   = threadIdx.x;
    const int qtile = blockIdx.x;          // 0..QTILES-1
    const int b     = blockIdx.y;          // 0..B-1
    const int z     = blockIdx.z;          // 0..2*SPLIT-1
    const int dir   = z & 1;               // 0: dist1 (q=xyz1,db=xyz2), 1: dist2
    const int split = z >> 1;              // 0..SPLIT-1

    const float* qbase = (dir == 0 ? xyz1 : xyz2) + b * NN * DD;
    const float* dbase = (dir == 0 ? xyz2 : xyz1) + b * NN * DD;

    // ---- stage db slice into LDS (SoA), coalesced ----
    const float* g = dbase + split * SLICE * DD;
    for (int idx = tid; idx < SLICE * DD; idx += TPB) {
        float v = g[idx];
        int p = idx / 3;
        int c = idx - 3 * p;
        (c == 0 ? sx : (c == 1 ? sy : sz))[p] = v;
    }
    __syncthreads();
    // ---- compute h per db point (SLICE == TPB: one each) ----
    {
        float x = sx[tid], y = sy[tid], zz = sz[tid];
        sh[tid] = fmaf(x, x, fmaf(y, y, zz * zz));
    }

    // ---- load my 8 query points; precompute a = -2q, s1 = ||q||^2 ----
    const int q0 = qtile * QPB + tid;
    float ax[QPT], ay[QPT], az[QPT], s1[QPT], bA[QPT], bB[QPT];
#pragma unroll
    for (int i = 0; i < QPT; ++i) {
        const float* p = qbase + (q0 + i * TPB) * DD;
        float x = p[0], y = p[1], zz = p[2];
        ax[i] = -2.0f * x;
        ay[i] = -2.0f * y;
        az[i] = -2.0f * zz;
        s1[i] = fmaf(x, x, fmaf(y, y, zz * zz));
        bA[i] = 3.0e38f;
        bB[i] = 3.0e38f;
    }
    __syncthreads();

    // ---- sweep db slice, 8 points/iter via broadcast b128 reads ----
    for (int j = 0; j < SLICE; j += 8) {
        float4 X[2], Y[2], Z[2], H[2];
#pragma unroll
        for (int u = 0; u < 2; ++u) {
            X[u] = *(const float4*)&sx[j + 4 * u];
            Y[u] = *(const float4*)&sy[j + 4 * u];
            Z[u] = *(const float4*)&sz[j + 4 * u];
            H[u] = *(const float4*)&sh[j + 4 * u];
        }
#pragma unroll
        for (int u = 0; u < 2; ++u) {
#pragma unroll
            for (int i = 0; i < QPT; ++i) {
                float t0 = fmaf(ax[i], X[u].x, fmaf(ay[i], Y[u].x, fmaf(az[i], Z[u].x, H[u].x)));
                float t1 = fmaf(ax[i], X[u].y, fmaf(ay[i], Y[u].y, fmaf(az[i], Z[u].y, H[u].y)));
                float t2 = fmaf(ax[i], X[u].z, fmaf(ay[i], Y[u].z, fmaf(az[i], Z[u].z, H[u].z)));
                float t3 = fmaf(ax[i], X[u].w, fmaf(ay[i], Y[u].w, fmaf(az[i], Z[u].w, H[u].w)));
                bA[i] = fminf(fminf(t0, t1), bA[i]);   // v_min3_f32 candidate
                bB[i] = fminf(fminf(t2, t3), bB[i]);
            }
        }
    }

    // ---- combine partials across M-splits via int atomicMin (d2 >= 0) ----
    const int obase = dir * (BB * NN) + b * NN + q0;
#pragma unroll
    for (int i = 0; i < QPT; ++i) {
        float best = fmaxf(s1[i] + fminf(bA[i], bB[i]), 0.0f);
        atomicMin((int*)out + obase + i * TPB, __float_as_int(best));
    }
}

extern "C" void kernel_launch(void* const* d_in, const int* in_sizes, int n_in,
                              void* d_out, int out_size, void* d_ws, size_t ws_size,
                              hipStream_t stream) {
    const float* xyz1 = (const float*)d_in[0];
    const float* xyz2 = (const float*)d_in[1];
    float* out = (float*)d_out;

    // init output to +big (harness poisons d_out; must rewrite every call)
    hipLaunchKernelGGL(chamfer_init_out, dim3(2 * BB * NN / 256), dim3(256), 0, stream, out);

    dim3 grid(QTILES, BB, 2 * SPLIT);
    hipLaunchKernelGGL(chamfer_main, grid, dim3(TPB), 0, stream, xyz1, xyz2, out);
}